// Round 3
// baseline (182.411 us; speedup 1.0000x reference)
//
#include <hip/hip_runtime.h>

// Problem constants: B=2, S=2048, D_MODEL=1024, H=16, DK=64.
// Workspace need: ~20.5 MB (og aliases st16; see kernel_launch).

#define LOG2E 1.44269504088896f

using f16   = _Float16;
using f16x4 = __attribute__((ext_vector_type(4))) _Float16;
using f16x8 = __attribute__((ext_vector_type(8))) _Float16;
using f32x4 = __attribute__((ext_vector_type(4))) float;

#define GLDS16(g, l) __builtin_amdgcn_global_load_lds((const __attribute__((address_space(1))) void*)(g), (__attribute__((address_space(3))) void*)(l), 16, 0, 0)
#define GLDS4(g, l)  __builtin_amdgcn_global_load_lds((const __attribute__((address_space(1))) void*)(g), (__attribute__((address_space(3))) void*)(l), 4, 0, 0)

// ---------------------------------------------------------------------------
// K1: blocks 0-1023:   s[b,h,k] = states·Wa  (wave per row) + states->fp16
//     blocks 1024-2047: gsig[b,q,h] = sigmoid(states·Wg + bg)
//     blocks 2048-3071: Wv/Wo -> fp16; cb<512: mask absmax partials
// ---------------------------------------------------------------------------
__global__ __launch_bounds__(256) void k_prep(
    const float* __restrict__ states, const float* __restrict__ mask,
    const float* __restrict__ Wa, const float* __restrict__ Wv,
    const float* __restrict__ Wg, const float* __restrict__ Wo,
    const float* __restrict__ bg,
    f16* __restrict__ st16, f16* __restrict__ Wv16, f16* __restrict__ Wo16,
    float* __restrict__ sbuf, float* __restrict__ gsig, float* __restrict__ partial)
{
  __shared__ float ws[16 * 1024];   // 64 KB
  const int bid = blockIdx.x;
  const int t   = threadIdx.x;
  if (bid < 2048) {
    const bool is_g = bid >= 1024;
    const float* W = is_g ? Wg : Wa;
    for (int i = t; i < 4096; i += 256)
      ((float4*)ws)[i] = ((const float4*)W)[i];
    __syncthreads();
    const int wid = t >> 6, lane = t & 63;
    const int row = (bid & 1023) * 4 + wid;           // 0..4095
    const float* sp = states + (size_t)row * 1024 + lane * 16;
    float x[16];
    #pragma unroll
    for (int j = 0; j < 4; ++j) {
      float4 v = ((const float4*)sp)[j];
      x[j*4+0]=v.x; x[j*4+1]=v.y; x[j*4+2]=v.z; x[j*4+3]=v.w;
    }
    if (!is_g) {
      f16x8 h0, h1;
      #pragma unroll
      for (int j = 0; j < 8; ++j) { h0[j] = (f16)x[j]; h1[j] = (f16)x[8+j]; }
      f16* dp = st16 + (size_t)row * 1024 + lane * 16;
      *(f16x8*)dp = h0; *(f16x8*)(dp + 8) = h1;
    }
    const int b = row >> 11, q = row & 2047;
    for (int h = 0; h < 16; ++h) {
      const float4* wr4 = (const float4*)(ws + h * 1024 + lane * 16);
      float acc = 0.f;
      #pragma unroll
      for (int j = 0; j < 4; ++j) {
        float4 wv4 = wr4[j];
        acc = fmaf(x[j*4+0], wv4.x, acc);
        acc = fmaf(x[j*4+1], wv4.y, acc);
        acc = fmaf(x[j*4+2], wv4.z, acc);
        acc = fmaf(x[j*4+3], wv4.w, acc);
      }
      #pragma unroll
      for (int off = 32; off; off >>= 1) acc += __shfl_xor(acc, off, 64);
      if (lane == 0) {
        if (!is_g) sbuf[(size_t)(b * 16 + h) * 2048 + q] = acc;
        else       gsig[(size_t)row * 16 + h] = 1.f / (1.f + __expf(-(acc + bg[h])));
      }
    }
  } else {
    const int cb = bid - 2048;                         // 0..1023
    { // weight convert: 2 M halves total, 2048 per block
      int idx = cb * 2048 + t * 8;
      const float* src; f16* dst;
      if (idx < 1048576) { src = Wv + idx;             dst = Wv16 + idx; }
      else               { src = Wo + (idx - 1048576); dst = Wo16 + (idx - 1048576); }
      float4 v0 = ((const float4*)src)[0];
      float4 v1 = ((const float4*)src)[1];
      f16x8 h;
      h[0]=(f16)v0.x; h[1]=(f16)v0.y; h[2]=(f16)v0.z; h[3]=(f16)v0.w;
      h[4]=(f16)v1.x; h[5]=(f16)v1.y; h[6]=(f16)v1.z; h[7]=(f16)v1.w;
      *(f16x8*)dst = h;
    }
    if (cb < 512) {
      // mask absmax partial: 512 chunks x 16384 floats = 8,388,608 = B*S*S
      const float4* mp = (const float4*)(mask + (size_t)cb * 16384);
      float mx = 0.f;
      for (int i = 0; i < 16; ++i) {
        float4 v = mp[t + i * 256];
        mx = fmaxf(mx, fmaxf(fmaxf(fabsf(v.x), fabsf(v.y)), fmaxf(fabsf(v.z), fabsf(v.w))));
      }
      #pragma unroll
      for (int off = 32; off; off >>= 1) mx = fmaxf(mx, __shfl_xor(mx, off, 64));
      if ((t & 63) == 0) ws[t >> 6] = mx;
      __syncthreads();
      if (t == 0) partial[cb] = fmaxf(fmaxf(ws[0], ws[1]), fmaxf(ws[2], ws[3]));
    }
  }
}

// ---------------------------------------------------------------------------
// K2: L[b,h] = max_k s[b,h,k] + head_scale[h] * max|mask_b|
// ---------------------------------------------------------------------------
__global__ __launch_bounds__(64) void k_lmax(
    const float* __restrict__ sbuf, const float* __restrict__ partial,
    const float* __restrict__ hs, float* __restrict__ Lbuf)
{
  const int bh = blockIdx.x, l = threadIdx.x;
  float mx = -1e30f;
  for (int i = l; i < 2048; i += 64) mx = fmaxf(mx, sbuf[(size_t)bh * 2048 + i]);
  float mm = 0.f;
  const int b = bh >> 4;
  for (int i = l; i < 256; i += 64) mm = fmaxf(mm, partial[b * 256 + i]);
  #pragma unroll
  for (int off = 32; off; off >>= 1) {
    mx = fmaxf(mx, __shfl_xor(mx, off, 64));
    mm = fmaxf(mm, __shfl_xor(mm, off, 64));
  }
  if (l == 0) Lbuf[bh] = mx + hs[bh & 15] * mm;
}

// ---------------------------------------------------------------------------
// K3: vt[(b*1024 + n)][k] = fp16( states[b,k,:]·Wv[n,:] + bv[n] ), V^T layout.
// 128x128 tile, BK=32, double-buffered global_load_lds + counted vmcnt.
// ---------------------------------------------------------------------------
__global__ __launch_bounds__(256) void k_gemm_v(
    const f16* __restrict__ A, const f16* __restrict__ Bw,
    const float* __restrict__ bv, f16* __restrict__ vt)
{
  __shared__ f16 As[8192], Bs[8192];   // 2 buffers each
  const int t = threadIdx.x, wid = t >> 6, lane = t & 63;
  const int r0 = blockIdx.y * 128, n0 = blockIdx.x * 128;
  const int wr = wid >> 1, wc = wid & 1;
  f32x4 acc[4][4] = {};
  const int srow  = t >> 2;
  const int sunit = (t & 3) ^ ((srow >> 1) & 3);
  const f16* ga0 = A  + (size_t)(r0 + srow) * 1024      + sunit * 8;
  const f16* ga1 = A  + (size_t)(r0 + 64 + srow) * 1024 + sunit * 8;
  const f16* gb0 = Bw + (size_t)(n0 + srow) * 1024      + sunit * 8;
  const f16* gb1 = Bw + (size_t)(n0 + 64 + srow) * 1024 + sunit * 8;
  int ra[4], rb[4];
  #pragma unroll
  for (int m = 0; m < 4; ++m) {
    int rr = wr * 64 + m * 16 + (lane & 15);
    ra[m] = rr * 32 + (((lane >> 4) ^ ((rr >> 1) & 3)) * 8);
    rr = wc * 64 + m * 16 + (lane & 15);
    rb[m] = rr * 32 + (((lane >> 4) ^ ((rr >> 1) & 3)) * 8);
  }
  const int ldst = wid * 512;
  #define STAGE_G(kt, bb) do { const int k0_ = (kt) * 32; \
      GLDS16(ga0 + k0_, As + (bb)*4096 + ldst); \
      GLDS16(ga1 + k0_, As + (bb)*4096 + 2048 + ldst); \
      GLDS16(gb0 + k0_, Bs + (bb)*4096 + ldst); \
      GLDS16(gb1 + k0_, Bs + (bb)*4096 + 2048 + ldst); } while(0)
  STAGE_G(0, 0);
  for (int kt = 0; kt < 32; ++kt) {
    const int cur = kt & 1;
    if (kt < 31) {
      STAGE_G(kt + 1, cur ^ 1);
      asm volatile("s_waitcnt vmcnt(4)" ::: "memory");
    } else {
      asm volatile("s_waitcnt vmcnt(0)" ::: "memory");
    }
    asm volatile("s_barrier" ::: "memory");
    f16x8 a[4], b[4];
    #pragma unroll
    for (int m = 0; m < 4; ++m) a[m] = *(const f16x8*)(As + cur*4096 + ra[m]);
    #pragma unroll
    for (int n = 0; n < 4; ++n) b[n] = *(const f16x8*)(Bs + cur*4096 + rb[n]);
    #pragma unroll
    for (int m = 0; m < 4; ++m)
      #pragma unroll
      for (int n = 0; n < 4; ++n)
        acc[m][n] = __builtin_amdgcn_mfma_f32_16x16x32_f16(a[m], b[n], acc[m][n], 0, 0, 0);
    asm volatile("s_waitcnt lgkmcnt(0)" ::: "memory");
    asm volatile("s_barrier" ::: "memory");
  }
  #undef STAGE_G
  const int b_ = r0 >> 11;
  #pragma unroll
  for (int n = 0; n < 4; ++n) {
    const int gn = n0 + wc * 64 + n * 16 + (lane & 15);
    const float bvv = bv[gn];
    #pragma unroll
    for (int m = 0; m < 4; ++m) {
      const int kb = (r0 & 2047) + wr * 64 + m * 16 + ((lane >> 4) << 2);
      f16x4 hv;
      #pragma unroll
      for (int r = 0; r < 4; ++r) hv[r] = (f16)(acc[m][n][r] + bvv);
      *(f16x4*)(vt + (size_t)(b_ * 1024 + gn) * 2048 + kb) = hv;
    }
  }
}

// ---------------------------------------------------------------------------
// K4: fused attention v2. Block = (hg, qt, b): 4 heads x 64 q-rows. 8 waves:
// wave = (head, kh) — head = wid>>1, k-half kh = wid&1 of each 64-k tile.
// Softmax computed DIRECTLY in MFMA A-fragment layout (no P LDS round-trip):
// lane owns q = m*16+(l&15), k = kh*32+(l>>4)*8+j. Mask tile staged once per
// block (shared by 4 heads). Double-buffered staging, counted vmcnt.
// Cross-kh accumulator reduce via LDS at the end. Epilogue: /den * sigmoid(g).
// ---------------------------------------------------------------------------
__global__ __launch_bounds__(512) void k_attn(
    const float* __restrict__ mask, const float* __restrict__ sbuf,
    const float* __restrict__ gsig, const float* __restrict__ hs,
    const float* __restrict__ Lbuf, const f16* __restrict__ vt,
    f16* __restrict__ og)
{
  __shared__ __align__(16) char lds_raw[102400];           // 100 KB
  float* mk   = (float*)lds_raw;               // 2 x [64 rows][16 slots x 4f] swizzled
  f16*   vs   = (f16*)(lds_raw + 32768);       // 2 x [4 heads][64 d][8 slots x 8h] swizzled
  float* stb  = (float*)(lds_raw + 98304);     // 2 x [4][64]
  float* den2 = (float*)(lds_raw + 100352);    // [2 kh][4 head][64 q]
  float* red  = (float*)lds_raw;               // alias (post-loop): [4][64][64] f32

  const int hg = blockIdx.x, qt = blockIdx.y, b = blockIdx.z;
  const int t = threadIdx.x, wid = t >> 6, lane = t & 63;
  const int head = wid >> 1, kh = wid & 1;
  const int lane15 = lane & 15, lg = lane >> 4;
  const int h = hg * 4 + head;
  const float L   = Lbuf[b * 16 + h];
  const float c2  = hs[h] * LOG2E;
  const float nLc = -L * LOG2E;

  const float* mbase = mask + (size_t)b * 4194304 + (size_t)(qt * 64) * 2048;
  const f16*   vtb   = vt + (size_t)(b * 1024 + hg * 256) * 2048;
  const float* sb    = sbuf + (size_t)(b * 16 + hg * 4) * 2048;

  // --- staging source precompute (k0-invariant) ---
  const int mrow = t >> 4, mcs = t & 15;                   // mask rows i*32+mrow
  const float* msrc0 = mbase + (size_t)mrow * 2048 + ((mcs ^ (mrow & 15)) * 4);
  const float* msrc1 = msrc0 + (size_t)32 * 2048;          // (32+mrow)&15 == mrow&15
  const int vd = t >> 3, vcs = t & 7;                      // V: head i, row d
  const f16* vsrc0 = vtb + (size_t)vd * 2048 + ((vcs ^ (vd & 7)) * 8);
  const float* ssrc = sb + (size_t)wid * 2048 + (t & 63);  // used by wid<4 only

  #define STAGE_A(kt, bb) do { const int k0_ = (kt) * 64; \
      GLDS16(msrc0 + k0_, mk + (bb)*4096 + t*4); \
      GLDS16(msrc1 + k0_, mk + (bb)*4096 + 2048 + t*4); \
      GLDS16(vsrc0 + k0_,                    vs + (bb)*16384 + t*8); \
      GLDS16(vsrc0 + (size_t)64*2048  + k0_, vs + (bb)*16384 + 4096  + t*8); \
      GLDS16(vsrc0 + (size_t)128*2048 + k0_, vs + (bb)*16384 + 8192  + t*8); \
      GLDS16(vsrc0 + (size_t)192*2048 + k0_, vs + (bb)*16384 + 12288 + t*8); \
      if (wid < 4) GLDS4(ssrc + k0_, stb + (bb)*256 + t); } while(0)

  // --- read-offset precompute (element units, cur-invariant) ---
  const int c0 = kh * 8 + lg * 2;
  int moff_a[4], moff_b[4];
  #pragma unroll
  for (int m = 0; m < 4; ++m) {
    const int q = m * 16 + lane15;
    moff_a[m] = q * 64 + ((c0 ^ (q & 15)) * 4);
    moff_b[m] = q * 64 + (((c0 + 1) ^ (q & 15)) * 4);
  }
  int voff[4];
  #pragma unroll
  for (int n = 0; n < 4; ++n) {
    const int d = n * 16 + lane15;
    voff[n] = (head * 64 + d) * 64 + (((kh * 4 + lg) ^ (d & 7)) * 8);
  }
  const int soff = head * 64 + kh * 32 + lg * 8;

  f32x4 acc[4][4] = {};
  float den[4] = {0.f, 0.f, 0.f, 0.f};

  STAGE_A(0, 0);
  for (int kt = 0; kt < 32; ++kt) {
    const int cur = kt & 1;
    if (kt < 31) {
      STAGE_A(kt + 1, cur ^ 1);
      if (wid < 4) asm volatile("s_waitcnt vmcnt(7)" ::: "memory");
      else         asm volatile("s_waitcnt vmcnt(6)" ::: "memory");
    } else {
      asm volatile("s_waitcnt vmcnt(0)" ::: "memory");
    }
    asm volatile("s_barrier" ::: "memory");

    const float* mkc = mk + cur * 4096;
    const f16*   vsc = vs + cur * 16384;
    const float* stc = stb + cur * 256 + soff;

    f32x4 s0 = *(const f32x4*)(stc);
    f32x4 s1 = *(const f32x4*)(stc + 4);
    float sx[8];
    #pragma unroll
    for (int e = 0; e < 4; ++e) {
      sx[e]     = fmaf(s0[e], LOG2E, nLc);
      sx[4 + e] = fmaf(s1[e], LOG2E, nLc);
    }
    f16x8 vf[4];
    #pragma unroll
    for (int n = 0; n < 4; ++n) vf[n] = *(const f16x8*)(vsc + voff[n]);

    #pragma unroll
    for (int m = 0; m < 4; ++m) {
      f32x4 ma = *(const f32x4*)(mkc + moff_a[m]);
      f32x4 mb = *(const f32x4*)(mkc + moff_b[m]);
      f16x8 af;
      float dl = 0.f;
      #pragma unroll
      for (int e = 0; e < 4; ++e) {
        float w = __builtin_amdgcn_exp2f(fmaf(c2, ma[e], sx[e]));
        dl += w; af[e] = (f16)w;
      }
      #pragma unroll
      for (int e = 0; e < 4; ++e) {
        float w = __builtin_amdgcn_exp2f(fmaf(c2, mb[e], sx[4 + e]));
        dl += w; af[4 + e] = (f16)w;
      }
      den[m] += dl;
      #pragma unroll
      for (int n = 0; n < 4; ++n)
        acc[m][n] = __builtin_amdgcn_mfma_f32_16x16x32_f16(af, vf[n], acc[m][n], 0, 0, 0);
    }
    asm volatile("s_waitcnt lgkmcnt(0)" ::: "memory");
    asm volatile("s_barrier" ::: "memory");
  }
  #undef STAGE_A

  // --- den: lane reduce (q = m*16+lane15 complete per kh) ---
  #pragma unroll
  for (int m = 0; m < 4; ++m) {
    den[m] += __shfl_xor(den[m], 16, 64);
    den[m] += __shfl_xor(den[m], 32, 64);
  }
  if (lane < 16) {
    #pragma unroll
    for (int m = 0; m < 4; ++m)
      den2[(kh * 4 + head) * 64 + m * 16 + lane] = den[m];
  }
  // --- dump half of acc for cross-kh sum: kh=1 dumps m{0,1}, kh=0 dumps m{2,3}
  const int mdump = kh ? 0 : 2;
  #pragma unroll
  for (int mm = 0; mm < 2; ++mm) {
    const int m = mdump + mm;
    #pragma unroll
    for (int n = 0; n < 4; ++n)
      #pragma unroll
      for (int r = 0; r < 4; ++r)
        red[(head * 64 + m * 16 + lg * 4 + r) * 64 + n * 16 + lane15] = acc[m][n][r];
  }
  __syncthreads();
  // --- finalize the other half: add partner's partial, scale, store ---
  const int mkeep = kh ? 2 : 0;
  #pragma unroll
  for (int mm = 0; mm < 2; ++mm) {
    const int m = mkeep + mm;
    #pragma unroll
    for (int r = 0; r < 4; ++r) {
      const int ql = m * 16 + lg * 4 + r;
      const float dt = den2[(0 + head) * 64 + ql] + den2[(4 + head) * 64 + ql];
      const int q = qt * 64 + ql;
      const float sc = gsig[(size_t)(b * 2048 + q) * 16 + h] / dt;
      #pragma unroll
      for (int n = 0; n < 4; ++n) {
        const float o = acc[m][n][r] + red[(head * 64 + ql) * 64 + n * 16 + lane15];
        og[(size_t)(b * 2048 + q) * 1024 + h * 64 + n * 16 + lane15] = (f16)(o * sc);
      }
    }
  }
}

// ---------------------------------------------------------------------------
// K5: out[r][n] = og[r,:]·Wo[n,:] + bo[n]  (f32 output), dbuf + counted vmcnt
// ---------------------------------------------------------------------------
__global__ __launch_bounds__(256) void k_gemm_out(
    const f16* __restrict__ A, const f16* __restrict__ Bw,
    const float* __restrict__ bo, float* __restrict__ out)
{
  __shared__ f16 As[8192], Bs[8192];
  const int t = threadIdx.x, wid = t >> 6, lane = t & 63;
  const int r0 = blockIdx.y * 128, n0 = blockIdx.x * 128;
  const int wr = wid >> 1, wc = wid & 1;
  f32x4 acc[4][4] = {};
  const int srow  = t >> 2;
  const int sunit = (t & 3) ^ ((srow >> 1) & 3);
  const f16* ga0 = A  + (size_t)(r0 + srow) * 1024      + sunit * 8;
  const f16* ga1 = A  + (size_t)(r0 + 64 + srow) * 1024 + sunit * 8;
  const f16* gb0 = Bw + (size_t)(n0 + srow) * 1024      + sunit * 8;
  const f16* gb1 = Bw + (size_t)(n0 + 64 + srow) * 1024 + sunit * 8;
  int ra[4], rb[4];
  #pragma unroll
  for (int m = 0; m < 4; ++m) {
    int rr = wr * 64 + m * 16 + (lane & 15);
    ra[m] = rr * 32 + (((lane >> 4) ^ ((rr >> 1) & 3)) * 8);
    rr = wc * 64 + m * 16 + (lane & 15);
    rb[m] = rr * 32 + (((lane >> 4) ^ ((rr >> 1) & 3)) * 8);
  }
  const int ldst = wid * 512;
  #define STAGE_G(kt, bb) do { const int k0_ = (kt) * 32; \
      GLDS16(ga0 + k0_, As + (bb)*4096 + ldst); \
      GLDS16(ga1 + k0_, As + (bb)*4096 + 2048 + ldst); \
      GLDS16(gb0 + k0_, Bs + (bb)*4096 + ldst); \
      GLDS16(gb1 + k0_, Bs + (bb)*4096 + 2048 + ldst); } while(0)
  STAGE_G(0, 0);
  for (int kt = 0; kt < 32; ++kt) {
    const int cur = kt & 1;
    if (kt < 31) {
      STAGE_G(kt + 1, cur ^ 1);
      asm volatile("s_waitcnt vmcnt(4)" ::: "memory");
    } else {
      asm volatile("s_waitcnt vmcnt(0)" ::: "memory");
    }
    asm volatile("s_barrier" ::: "memory");
    f16x8 a[4], b[4];
    #pragma unroll
    for (int m = 0; m < 4; ++m) a[m] = *(const f16x8*)(As + cur*4096 + ra[m]);
    #pragma unroll
    for (int n = 0; n < 4; ++n) b[n] = *(const f16x8*)(Bs + cur*4096 + rb[n]);
    #pragma unroll
    for (int m = 0; m < 4; ++m)
      #pragma unroll
      for (int n = 0; n < 4; ++n)
        acc[m][n] = __builtin_amdgcn_mfma_f32_16x16x32_f16(a[m], b[n], acc[m][n], 0, 0, 0);
    asm volatile("s_waitcnt lgkmcnt(0)" ::: "memory");
    asm volatile("s_barrier" ::: "memory");
  }
  #undef STAGE_G
  #pragma unroll
  for (int n = 0; n < 4; ++n) {
    const int gn = n0 + wc * 64 + n * 16 + (lane & 15);
    const float bov = bo[gn];
    #pragma unroll
    for (int m = 0; m < 4; ++m) {
      const int rbase = r0 + wr * 64 + m * 16 + ((lane >> 4) << 2);
      #pragma unroll
      for (int r = 0; r < 4; ++r)
        out[(size_t)(rbase + r) * 1024 + gn] = acc[m][n][r] + bov;
    }
  }
}

// ---------------------------------------------------------------------------
extern "C" void kernel_launch(void* const* d_in, const int* in_sizes, int n_in,
                              void* d_out, int out_size, void* d_ws, size_t ws_size,
                              hipStream_t stream)
{
  const float* states = (const float*)d_in[0];
  const float* mask   = (const float*)d_in[1];
  const float* hs     = (const float*)d_in[2];
  const float* Wa     = (const float*)d_in[3];
  const float* Wv     = (const float*)d_in[4];
  const float* bv     = (const float*)d_in[5];
  const float* Wg     = (const float*)d_in[6];
  const float* bg     = (const float*)d_in[7];
  const float* Wo     = (const float*)d_in[8];
  const float* bo     = (const float*)d_in[9];
  float* out = (float*)d_out;

  // workspace layout (bytes): total 21,497,984 (~20.5 MB). og aliases st16:
  // st16 is consumed by k_gemm_v before k_attn writes og (stream-ordered).
  char* ws = (char*)d_ws;
  f16*   st16    = (f16*)(ws);                   //  8 MB  states fp16 [4096][1024]
  f16*   og      = (f16*)(ws);                   //  8 MB  gated O fp16 (alias)
  f16*   Wv16    = (f16*)(ws + 8388608);         //  2 MB
  f16*   Wo16    = (f16*)(ws + 10485760);        //  2 MB
  float* sbuf    = (float*)(ws + 12582912);      // 256 KB s [32][2048]
  float* gsig    = (float*)(ws + 12845056);      // 256 KB sigmoid(g) [4096][16]
  f16*   vt      = (f16*)(ws + 13107200);        //  8 MB  V^T [2048][2048]
  float* partial = (float*)(ws + 21495808);      //  2 KB  mask absmax partials (512)
  float* Lbuf    = (float*)(ws + 21497856);      // 128 B  logit upper bounds

  k_prep<<<3072, 256, 0, stream>>>(states, mask, Wa, Wv, Wg, Wo, bg,
                                   st16, Wv16, Wo16, sbuf, gsig, partial);
  k_lmax<<<32, 64, 0, stream>>>(sbuf, partial, hs, Lbuf);
  k_gemm_v<<<dim3(8, 32), 256, 0, stream>>>(st16, Wv16, bv, vt);
  k_attn<<<dim3(4, 32, 2), 512, 0, stream>>>(mask, sbuf, gsig, hs, Lbuf, vt, og);
  k_gemm_out<<<dim3(8, 32), 256, 0, stream>>>(og, Wo16, bo, out);
}